// Round 3
// baseline (58.938 us; speedup 1.0000x reference)
//
#include <hip/hip_runtime.h>

#define Nn 512
#define Dd 128
#define Kk 2048
#define Cc 100
#define KC 8            // k-chunks per class
#define CHUNK 256       // cols per chunk (64 colgroups x 4)
#define G 8             // samples per pass
constexpr float INV_T = 1.0f / 0.07f;

// ws layout (floats):
// [0, 512)                  lpos[n]
// [512, 512+4096)           stats_m[n*KC+kc]
// [4608, 8704)              stats_s[n*KC+kc]

__global__ __launch_bounds__(256) void chunk_kernel(
    const float* __restrict__ q, const float* __restrict__ k,
    const float* __restrict__ queue, const int* __restrict__ labels,
    float* __restrict__ ws)
{
    const int c    = blockIdx.y;
    const int kc   = blockIdx.x;
    const int t    = threadIdx.x;
    const int gcol = t & 63;   // colgroup: 4 consecutive cols
    const int dq   = t >> 6;   // d-quarter: 32 d's per wave
    const int lane = t & 63;

    __shared__ int   s_list[Nn];
    __shared__ int   s_cnt;
    __shared__ float sq[Dd][G];              // staged q rows [d][s], 4 KB
    __shared__ float partial[3][G][4][65];   // d-quarter partials, padded, ~25 KB

    // wave-0 ballot scan: deterministic ordered list of samples with label c
    if (t < 64) {
        int cnt = 0;
        for (int base = 0; base < Nn; base += 64) {
            int lab = labels[base + t];
            unsigned long long m = __ballot(lab == c);
            if (lab == c) {
                int pos = __popcll(m & ((1ull << t) - 1ull));
                s_list[cnt + pos] = base + t;
            }
            cnt += __popcll(m);
        }
        if (t == 0) s_cnt = cnt;
    }
    __syncthreads();
    const int cnt = s_cnt;
    if (cnt == 0) return;

    float* lpos    = ws;
    float* stats_m = ws + Nn;
    float* stats_s = ws + Nn + Nn * KC;

    const int col0 = kc * CHUNK + gcol * 4;
    const float* qbase = queue + (size_t)c * ((size_t)Dd * Kk)
                       + (size_t)(dq * 32) * Kk + col0;

    for (int g0 = 0; g0 < cnt; g0 += G) {
        const int gs = min(G, cnt - g0);

        // stage q rows: sq[d][s] = q[list[g0+s]][d]
        for (int i = t; i < Dd * G; i += 256) {
            int d = i >> 3, s = i & 7;
            sq[d][s] = (s < gs) ? q[s_list[g0 + s] * Dd + d] : 0.f;
        }
        __syncthreads();

        // each thread: 4 cols (float4), 32 d's, G samples
        float4 acc[G];
        #pragma unroll
        for (int s = 0; s < G; ++s) acc[s] = make_float4(0.f, 0.f, 0.f, 0.f);

        #pragma unroll 8
        for (int d = 0; d < 32; ++d) {
            float4 v = *reinterpret_cast<const float4*>(qbase + (size_t)d * Kk);
            const float4 qA = *reinterpret_cast<const float4*>(&sq[dq * 32 + d][0]);
            const float4 qB = *reinterpret_cast<const float4*>(&sq[dq * 32 + d][4]);
            const float qs[8] = {qA.x, qA.y, qA.z, qA.w, qB.x, qB.y, qB.z, qB.w};
            #pragma unroll
            for (int s = 0; s < G; ++s) {
                acc[s].x = fmaf(qs[s], v.x, acc[s].x);
                acc[s].y = fmaf(qs[s], v.y, acc[s].y);
                acc[s].z = fmaf(qs[s], v.z, acc[s].z);
                acc[s].w = fmaf(qs[s], v.w, acc[s].w);
            }
        }

        // reduce the 4 d-quarters: waves 1..3 write, wave 0 accumulates
        if (dq > 0) {
            #pragma unroll
            for (int s = 0; s < G; ++s) {
                partial[dq - 1][s][0][gcol] = acc[s].x;
                partial[dq - 1][s][1][gcol] = acc[s].y;
                partial[dq - 1][s][2][gcol] = acc[s].z;
                partial[dq - 1][s][3][gcol] = acc[s].w;
            }
        }
        __syncthreads();

        if (dq == 0) {
            #pragma unroll
            for (int r = 0; r < 3; ++r) {
                #pragma unroll
                for (int s = 0; s < G; ++s) {
                    acc[s].x += partial[r][s][0][gcol];
                    acc[s].y += partial[r][s][1][gcol];
                    acc[s].z += partial[r][s][2][gcol];
                    acc[s].w += partial[r][s][3][gcol];
                }
            }

            // per-sample chunk softmax stats, wave 0 only
            float mym = 0.f, mys = 0.f;
            for (int s = 0; s < gs; ++s) {
                float lx = acc[s].x * INV_T, ly = acc[s].y * INV_T;
                float lz = acc[s].z * INV_T, lw = acc[s].w * INV_T;
                float m = fmaxf(fmaxf(lx, ly), fmaxf(lz, lw));
                #pragma unroll
                for (int off = 32; off >= 1; off >>= 1)
                    m = fmaxf(m, __shfl_xor(m, off, 64));
                float e = expf(lx - m) + expf(ly - m) + expf(lz - m) + expf(lw - m);
                #pragma unroll
                for (int off = 32; off >= 1; off >>= 1)
                    e += __shfl_xor(e, off, 64);
                if (lane == s) { mym = m; mys = e; }
            }
            if (lane < gs) {
                int n = s_list[g0 + lane];
                stats_m[n * KC + kc] = mym;
                stats_s[n * KC + kc] = mys;
                if (kc == 0) {
                    float lp = 0.f;
                    const float* krow = k + n * Dd;
                    #pragma unroll 8
                    for (int d = 0; d < Dd; ++d) lp = fmaf(sq[d][lane], krow[d], lp);
                    lpos[n] = lp * INV_T;
                }
            }
        }
        __syncthreads();
    }
}

__global__ __launch_bounds__(512) void finish_kernel(
    const float* __restrict__ ws, float* __restrict__ out)
{
    const int t = threadIdx.x;   // one thread per sample
    const float* lpos    = ws;
    const float* stats_m = ws + Nn;
    const float* stats_s = ws + Nn + Nn * KC;

    const float lp = lpos[t];
    float mm[KC], ss[KC];
    float m = lp;
    #pragma unroll
    for (int j = 0; j < KC; ++j) {
        mm[j] = stats_m[t * KC + j];
        ss[j] = stats_s[t * KC + j];
        m = fmaxf(m, mm[j]);
    }
    float sum = expf(lp - m);
    #pragma unroll
    for (int j = 0; j < KC; ++j) sum += ss[j] * expf(mm[j] - m);
    const float loss = logf(sum) + m - lp;

    __shared__ float red[512];
    red[t] = loss;
    __syncthreads();
    for (int s2 = 256; s2 > 0; s2 >>= 1) {
        if (t < s2) red[t] += red[t + s2];
        __syncthreads();
    }
    if (t == 0) out[0] = red[0] / (float)Nn;
}

extern "C" void kernel_launch(void* const* d_in, const int* in_sizes, int n_in,
                              void* d_out, int out_size, void* d_ws, size_t ws_size,
                              hipStream_t stream) {
    const float* q      = (const float*)d_in[0];
    const float* k      = (const float*)d_in[1];
    const float* queue  = (const float*)d_in[2];
    // d_in[3] = class_weights — unused by the reference computation
    const int* labels   = (const int*)d_in[4];
    float* out          = (float*)d_out;
    float* ws           = (float*)d_ws;

    dim3 grid(KC, Cc);
    chunk_kernel<<<grid, 256, 0, stream>>>(q, k, queue, labels, ws);
    finish_kernel<<<1, 512, 0, stream>>>(ws, out);
}